// Round 15
// baseline (92.819 us; speedup 1.0000x reference)
//
#include <hip/hip_runtime.h>
#include <math.h>

#define BB 4
#define SS 2048
#define HH 256
#define NHH 8
#define EPSV 1e-5f
#define NC 8
#define CHW (SS/NC)     /* 256 cols per Psum chunk (attn_sums) */
#define NCO 4           /* O chunk-groups in attn_pv (balanced tile split) */
/* 1/sqrt(256) * log2(e): Q pre-scaled so exp(s/16) == exp2(QK^T) */
#define QPRE 0.09016844005556021f

#if __has_builtin(__builtin_amdgcn_exp2f)
#define EXP2F(x) __builtin_amdgcn_exp2f(x)
#else
#define EXP2F(x) __expf((x) * 0.6931471805599453f)
#endif

typedef unsigned short ushortT;
typedef __attribute__((ext_vector_type(8))) short bf16x8;
typedef __attribute__((ext_vector_type(4))) float f32x4;

__device__ inline ushortT f2bf(float f) {          // RNE
    union { float f; unsigned int u; } x; x.f = f;
    unsigned int r = x.u + 0x7FFFu + ((x.u >> 16) & 1u);
    return (ushortT)(r >> 16);
}
__device__ inline ushortT f2bf_rz(float f) {       // truncate (hot path)
    union { float f; unsigned int u; } x; x.f = f;
    return (ushortT)(x.u >> 16);
}
__device__ inline float bf2f(ushortT u) {
    union { unsigned int i; float f; } x; x.i = ((unsigned int)u) << 16;
    return x.f;
}

// ---------------- fused QKV MFMA GEMM; reads x and W fp32 directly (converts
// + transposes W in staging); Q pre-scaled by QPRE; V stored transposed.
// blockIdx.y==12: 128 side blocks transpose W1/W2 -> Wtb (for ffn_fused)
// and write out_len; race-free (no reader of Wtb z=3/4 in this kernel).
__global__ __launch_bounds__(256) void gemm_qkv(const float* __restrict__ X,
        const int* __restrict__ L, float* __restrict__ out_len,
        const float* __restrict__ Wq, const float* __restrict__ bq,
        const float* __restrict__ Wk, const float* __restrict__ bk,
        const float* __restrict__ Wv, const float* __restrict__ bv,
        const float* __restrict__ W1, const float* __restrict__ W2,
        ushortT* __restrict__ Wtb,
        ushortT* __restrict__ Qb, ushortT* __restrict__ Kb,
        ushortT* __restrict__ Vt) {
    __shared__ ushortT As[64][264];
    __shared__ ushortT Ws[64][264];
    const int tid = threadIdx.x;
    if (blockIdx.y == 12) {                    // W1/W2 transpose side blocks
        const int wb = blockIdx.x;             // 0..127
        if (wb == 0 && tid < BB) out_len[tid] = (float)L[tid];
        const int z = 3 + (wb >> 6);
        const int rem = wb & 63;
        const int k0 = (rem >> 3) << 5, n0q = (rem & 7) << 5;
        const float* W = (z == 3) ? W1 : W2;
        float (*tile)[33] = (float(*)[33])&As[0][0];
        const int r = tid >> 3, c4 = (tid & 7) << 2;
        float4 v = *(const float4*)(W + (size_t)(k0 + r) * HH + n0q + c4);
        tile[r][c4+0] = v.x; tile[r][c4+1] = v.y;
        tile[r][c4+2] = v.z; tile[r][c4+3] = v.w;
        __syncthreads();
        ushort4 o;
        o.x = f2bf(tile[c4+0][r]); o.y = f2bf(tile[c4+1][r]);
        o.z = f2bf(tile[c4+2][r]); o.w = f2bf(tile[c4+3][r]);
        *(ushort4*)(Wtb + (size_t)z * 65536 + (size_t)(n0q + r) * HH + k0 + c4) = o;
        return;
    }
    const int wsel = blockIdx.y >> 2;
    const int n0 = (blockIdx.y & 3) << 6;
    const float* W = (wsel == 0) ? Wq : (wsel == 1) ? Wk : Wv;
    const float* bias = (wsel == 0) ? bq : (wsel == 1) ? bk : bv;
    const int m0 = blockIdx.x << 6;
    // stage x strip (fp32 -> bf16)
    #pragma unroll
    for (int t = 0; t < 8; ++t) {
        const int f = t * 256 + tid;
        const int r = f >> 5;
        const int cc = (f & 31) << 3;
        const float* xrow = X + (size_t)(m0 + r) * HH + cc;
        float4 v0 = *(const float4*)xrow;
        float4 v1 = *(const float4*)(xrow + 4);
        bf16x8 o;
        o[0] = (short)f2bf(v0.x); o[1] = (short)f2bf(v0.y);
        o[2] = (short)f2bf(v0.z); o[3] = (short)f2bf(v0.w);
        o[4] = (short)f2bf(v1.x); o[5] = (short)f2bf(v1.y);
        o[6] = (short)f2bf(v1.z); o[7] = (short)f2bf(v1.w);
        *(bf16x8*)&As[r][cc] = o;
    }
    // stage W slice transposed: Ws[n-n0][k] = bf16(W[k][n]); thread owns one
    // n-column, packs 4 consecutive k into a single aligned b64 store.
    {
        const int q = tid >> 6, ln = tid & 63;
        #pragma unroll
        for (int kg = q * 64; kg < q * 64 + 64; kg += 4) {
            ushort4 o;
            o.x = f2bf(W[(size_t)(kg + 0) * HH + n0 + ln]);
            o.y = f2bf(W[(size_t)(kg + 1) * HH + n0 + ln]);
            o.z = f2bf(W[(size_t)(kg + 2) * HH + n0 + ln]);
            o.w = f2bf(W[(size_t)(kg + 3) * HH + n0 + ln]);
            *(ushort4*)&Ws[ln][kg] = o;
        }
    }
    __syncthreads();
    const int w = tid >> 6, lane = tid & 63;
    const int lg = lane >> 4, lc = lane & 15;
    const int wr = (w & 1) << 5, wc = (w >> 1) << 5;
    f32x4 acc[2][2];
    const f32x4 z4 = {0.f, 0.f, 0.f, 0.f};
    acc[0][0] = z4; acc[0][1] = z4; acc[1][0] = z4; acc[1][1] = z4;
    #pragma unroll
    for (int k0 = 0; k0 < 256; k0 += 32) {
        bf16x8 a0 = *(const bf16x8*)&As[wr + lc][k0 + lg*8];
        bf16x8 a1 = *(const bf16x8*)&As[wr + 16 + lc][k0 + lg*8];
        bf16x8 b0 = *(const bf16x8*)&Ws[wc + lc][k0 + lg*8];
        bf16x8 b1 = *(const bf16x8*)&Ws[wc + 16 + lc][k0 + lg*8];
        acc[0][0] = __builtin_amdgcn_mfma_f32_16x16x32_bf16(a0, b0, acc[0][0], 0, 0, 0);
        acc[0][1] = __builtin_amdgcn_mfma_f32_16x16x32_bf16(a0, b1, acc[0][1], 0, 0, 0);
        acc[1][0] = __builtin_amdgcn_mfma_f32_16x16x32_bf16(a1, b0, acc[1][0], 0, 0, 0);
        acc[1][1] = __builtin_amdgcn_mfma_f32_16x16x32_bf16(a1, b1, acc[1][1], 0, 0, 0);
    }
    ushortT* Out = (wsel == 0) ? Qb : Kb;
    #pragma unroll
    for (int RH = 0; RH < 2; ++RH)
        #pragma unroll
        for (int CH = 0; CH < 2; ++CH) {
            const int col = n0 + wc + CH*16 + lc;
            const float bvv = bias[col];
            float v[4];
            #pragma unroll
            for (int r = 0; r < 4; ++r) {
                v[r] = acc[RH][CH][r] + bvv;
                if (wsel == 0) v[r] *= QPRE;
            }
            if (wsel < 2) {
                #pragma unroll
                for (int r = 0; r < 4; ++r) {
                    const int row = m0 + wr + RH*16 + lg*4 + r;
                    Out[(size_t)row * HH + col] = f2bf(v[r]);
                }
            } else {
                const int row0 = m0 + wr + RH*16 + lg*4;
                const int bidx = row0 >> 11, s0 = row0 & (SS - 1);
                ushort4 o;
                o.x = f2bf(v[0]); o.y = f2bf(v[1]); o.z = f2bf(v[2]); o.w = f2bf(v[3]);
                *(ushort4*)(Vt + ((size_t)(bidx * HH + col)) * SS + s0) = o;
            }
        }
}

// ---------------- fully fused FFN: X1N = LN(x + sum OPart); F1 = gelu(X1N@W1
// + b1) held in LDS; out = LN(F1@W2 + b2 + X1N). Block = 32-row strip x 256
// cols, 512 thr (8 waves), 1 block/CU. Row-local: no cross-block deps.
__global__ __launch_bounds__(512) void ffn_fused(const float* __restrict__ x,
        const ushortT* __restrict__ OPart, const int* __restrict__ lengths,
        const float* __restrict__ g1, const float* __restrict__ be1,
        const ushortT* __restrict__ W1t, const float* __restrict__ b1,
        const ushortT* __restrict__ W2t, const float* __restrict__ b2,
        const float* __restrict__ g2, const float* __restrict__ be2,
        float* __restrict__ X1N, float* __restrict__ out) {
    __shared__ ushortT Ws[256][264];       // W1t, then W2t
    __shared__ ushortT As[32][264];        // X1Nb strip, then F1b strip
    __shared__ float redA[8][32];
    __shared__ float redB[8][32];
    const int tid = threadIdx.x;
    const int m0 = blockIdx.x << 5;
    // stage W1t (full 256 x 256)
    #pragma unroll
    for (int t = 0; t < 16; ++t) {
        const int f = t * 512 + tid;
        const int r = f >> 5;
        const int cc = (f & 31) << 3;
        *(bf16x8*)&Ws[r][cc] = *(const bf16x8*)(W1t + (size_t)r * HH + cc);
    }
    const int w = tid >> 6, lane = tid & 63;
    const int lg = lane >> 4, lc = lane & 15;
    // LN phase: wave w owns rows m0 + w*4 .. +3; lane covers cols lane*4..+3
    const int len = lengths[m0 >> 11];
    const int col0 = lane << 2;
    #pragma unroll
    for (int rr = 0; rr < 4; ++rr) {
        const int row = m0 + w * 4 + rr;
        const int i = row & (SS - 1);
        const size_t base = (size_t)row * HH;
        float4 v = *(const float4*)(x + base + col0);
        if (i < len) {
            const int ncv = min(NCO, (i >> 5) + 1);
            for (int cc = 0; cc < ncv; ++cc) {
                ushort4 o = *(const ushort4*)(OPart +
                    (size_t)cc * ((size_t)BB * SS * HH) + base + col0);
                v.x += bf2f(o.x); v.y += bf2f(o.y);
                v.z += bf2f(o.z); v.w += bf2f(o.w);
            }
        }
        float s = v.x + v.y + v.z + v.w;
        #pragma unroll
        for (int o = 1; o < 64; o <<= 1) s += __shfl_xor(s, o);
        const float mu = s * 0.00390625f;
        float4 d = make_float4(v.x - mu, v.y - mu, v.z - mu, v.w - mu);
        float q = d.x*d.x + d.y*d.y + d.z*d.z + d.w*d.w;
        #pragma unroll
        for (int o = 1; o < 64; o <<= 1) q += __shfl_xor(q, o);
        const float rs = rsqrtf(q * 0.00390625f + EPSV);
        float4 res;
        res.x = d.x * rs * g1[col0+0] + be1[col0+0];
        res.y = d.y * rs * g1[col0+1] + be1[col0+1];
        res.z = d.z * rs * g1[col0+2] + be1[col0+2];
        res.w = d.w * rs * g1[col0+3] + be1[col0+3];
        *(float4*)(X1N + base + col0) = res;
        ushort4 rb;
        rb.x = f2bf(res.x); rb.y = f2bf(res.y);
        rb.z = f2bf(res.z); rb.w = f2bf(res.w);
        *(ushort4*)&As[w * 4 + rr][col0] = rb;
    }
    __syncthreads();
    // MFMA phase 1: wave w -> n-tile (w>>1), col-half (w&1); F1 = gelu(.)
    const int n0 = (w >> 1) << 6;
    const int ch = (w & 1) << 5;
    f32x4 acc[2][2];
    const f32x4 z4 = {0.f, 0.f, 0.f, 0.f};
    acc[0][0] = z4; acc[0][1] = z4; acc[1][0] = z4; acc[1][1] = z4;
    #pragma unroll
    for (int k0 = 0; k0 < 256; k0 += 32) {
        bf16x8 a0 = *(const bf16x8*)&As[lc][k0 + lg*8];
        bf16x8 a1 = *(const bf16x8*)&As[16 + lc][k0 + lg*8];
        bf16x8 b0 = *(const bf16x8*)&Ws[n0 + ch + lc][k0 + lg*8];
        bf16x8 b1 = *(const bf16x8*)&Ws[n0 + ch + 16 + lc][k0 + lg*8];
        acc[0][0] = __builtin_amdgcn_mfma_f32_16x16x32_bf16(a0, b0, acc[0][0], 0, 0, 0);
        acc[0][1] = __builtin_amdgcn_mfma_f32_16x16x32_bf16(a0, b1, acc[0][1], 0, 0, 0);
        acc[1][0] = __builtin_amdgcn_mfma_f32_16x16x32_bf16(a1, b0, acc[1][0], 0, 0, 0);
        acc[1][1] = __builtin_amdgcn_mfma_f32_16x16x32_bf16(a1, b1, acc[1][1], 0, 0, 0);
    }
    // gelu in regs
    #pragma unroll
    for (int RH = 0; RH < 2; ++RH)
        #pragma unroll
        for (int CH = 0; CH < 2; ++CH) {
            const float bv = b1[n0 + ch + CH*16 + lc];
            #pragma unroll
            for (int r = 0; r < 4; ++r) {
                float v = acc[RH][CH][r] + bv;
                acc[RH][CH][r] = 0.5f * v * (1.0f + erff(v * 0.70710678118f));
            }
        }
    __syncthreads();   // all MFMA1 reads of As/Ws complete
    // write F1 (bf16) into As; restage W2t into Ws
    #pragma unroll
    for (int RH = 0; RH < 2; ++RH)
        #pragma unroll
        for (int CH = 0; CH < 2; ++CH)
            #pragma unroll
            for (int r = 0; r < 4; ++r)
                As[RH*16 + lg*4 + r][n0 + ch + CH*16 + lc] = f2bf(acc[RH][CH][r]);
    #pragma unroll
    for (int t = 0; t < 16; ++t) {
        const int f = t * 512 + tid;
        const int r = f >> 5;
        const int cc = (f & 31) << 3;
        *(bf16x8*)&Ws[r][cc] = *(const bf16x8*)(W2t + (size_t)r * HH + cc);
    }
    __syncthreads();
    // MFMA phase 2: F2 = F1 @ W2
    acc[0][0] = z4; acc[0][1] = z4; acc[1][0] = z4; acc[1][1] = z4;
    #pragma unroll
    for (int k0 = 0; k0 < 256; k0 += 32) {
        bf16x8 a0 = *(const bf16x8*)&As[lc][k0 + lg*8];
        bf16x8 a1 = *(const bf16x8*)&As[16 + lc][k0 + lg*8];
        bf16x8 b0 = *(const bf16x8*)&Ws[n0 + ch + lc][k0 + lg*8];
        bf16x8 b1 = *(const bf16x8*)&Ws[n0 + ch + 16 + lc][k0 + lg*8];
        acc[0][0] = __builtin_amdgcn_mfma_f32_16x16x32_bf16(a0, b0, acc[0][0], 0, 0, 0);
        acc[0][1] = __builtin_amdgcn_mfma_f32_16x16x32_bf16(a0, b1, acc[0][1], 0, 0, 0);
        acc[1][0] = __builtin_amdgcn_mfma_f32_16x16x32_bf16(a1, b0, acc[1][0], 0, 0, 0);
        acc[1][1] = __builtin_amdgcn_mfma_f32_16x16x32_bf16(a1, b1, acc[1][1], 0, 0, 0);
    }
    // v = acc + b2 + X1N; per-row partial sums over this wave's 32 cols
    float v[2][2][4];
    float rs2[2][4] = {};
    #pragma unroll
    for (int RH = 0; RH < 2; ++RH)
        #pragma unroll
        for (int CH = 0; CH < 2; ++CH) {
            const int col = n0 + ch + CH*16 + lc;
            const float bv = b2[col];
            #pragma unroll
            for (int r = 0; r < 4; ++r) {
                const int row = m0 + RH*16 + lg*4 + r;
                float vv = acc[RH][CH][r] + bv + X1N[(size_t)row * HH + col];
                v[RH][CH][r] = vv;
                rs2[RH][r] += vv;
            }
        }
    #pragma unroll
    for (int RH = 0; RH < 2; ++RH)
        #pragma unroll
        for (int r = 0; r < 4; ++r) {
            rs2[RH][r] += __shfl_xor(rs2[RH][r], 1);
            rs2[RH][r] += __shfl_xor(rs2[RH][r], 2);
            rs2[RH][r] += __shfl_xor(rs2[RH][r], 4);
            rs2[RH][r] += __shfl_xor(rs2[RH][r], 8);
        }
    if (lc == 0) {
        #pragma unroll
        for (int RH = 0; RH < 2; ++RH)
            #pragma unroll
            for (int r = 0; r < 4; ++r)
                redA[w][RH*16 + lg*4 + r] = rs2[RH][r];
    }
    __syncthreads();
    float mu2[2][4];
    #pragma unroll
    for (int RH = 0; RH < 2; ++RH)
        #pragma unroll
        for (int r = 0; r < 4; ++r) {
            const int rl = RH*16 + lg*4 + r;
            mu2[RH][r] = (redA[0][rl] + redA[1][rl] + redA[2][rl] + redA[3][rl]
                        + redA[4][rl] + redA[5][rl] + redA[6][rl] + redA[7][rl])
                       * 0.00390625f;
        }
    float qs[2][4] = {};
    #pragma unroll
    for (int RH = 0; RH < 2; ++RH)
        #pragma unroll
        for (int CH = 0; CH < 2; ++CH)
            #pragma unroll
            for (int r = 0; r < 4; ++r) {
                const float d = v[RH][CH][r] - mu2[RH][r];
                qs[RH][r] += d * d;
            }
    #pragma unroll
    for (int RH = 0; RH < 2; ++RH)
        #pragma unroll
        for (int r = 0; r < 4; ++r) {
            qs[RH][r] += __shfl_xor(qs[RH][r], 1);
            qs[RH][r] += __shfl_xor(qs[RH][r], 2);
            qs[RH][r] += __shfl_xor(qs[RH][r], 4);
            qs[RH][r] += __shfl_xor(qs[RH][r], 8);
        }
    if (lc == 0) {
        #pragma unroll
        for (int RH = 0; RH < 2; ++RH)
            #pragma unroll
            for (int r = 0; r < 4; ++r)
                redB[w][RH*16 + lg*4 + r] = qs[RH][r];
    }
    __syncthreads();
    #pragma unroll
    for (int RH = 0; RH < 2; ++RH)
        #pragma unroll
        for (int r = 0; r < 4; ++r) {
            const int rl = RH*16 + lg*4 + r;
            const float var = (redB[0][rl] + redB[1][rl] + redB[2][rl] + redB[3][rl]
                             + redB[4][rl] + redB[5][rl] + redB[6][rl] + redB[7][rl])
                            * 0.00390625f;
            const float rq = rsqrtf(var + EPSV);
            const int row = m0 + rl;
            #pragma unroll
            for (int CH = 0; CH < 2; ++CH) {
                const int col = n0 + ch + CH*16 + lc;
                out[(size_t)row * HH + col] =
                    (v[RH][CH][r] - mu2[RH][r]) * rq * g2[col] + be2[col];
            }
        }
}

// ---------------- attention pass 1: partial exp2-sums per (chunk, head, row)
// 64-ROW Q-tiles. Also zero-fills the INACTIVE cols of its out_mean chunk.
__global__ __launch_bounds__(512) void attn_sums(const ushortT* __restrict__ Qb,
        const ushortT* __restrict__ Kb, const int* __restrict__ lengths,
        float* __restrict__ Psum, float* __restrict__ out_mean) {
    const int b = blockIdx.z, c = blockIdx.y;
    const int i0 = (31 - blockIdx.x) << 6;    // 64-row tiles, reversed dispatch
    const int len = lengths[b];
    const int tid = threadIdx.x;
    const int w = tid >> 6, lane = tid & 63;
    // zero inactive cols of this chunk; per-row T from its 32-row block
    #pragma unroll
    for (int rr = 0; rr < 8; ++rr) {
        const int row = i0 + w * 8 + rr;
        const int i032 = row & ~31;
        const int Tr = (i032 < len) ? ((min(i032 + 31, len - 1) >> 5) + 1) : 0;
        const int zs = max(Tr * 32 - c * CHW, 0);
        const int col = zs + (lane << 2);
        if (zs < CHW && col < CHW)
            *(float4*)(out_mean + ((size_t)(b * SS + row)) * SS + c * CHW + col)
                = make_float4(0.f, 0.f, 0.f, 0.f);
    }
    const int jmax = min(i0 + 63, len - 1);
    const int jstart = c * CHW;
    if (i0 >= len || jstart > jmax) return;   // never read downstream
    const int lg = lane >> 4, lc = lane & 15;
    bf16x8 qf[4];
    #pragma unroll
    for (int RH = 0; RH < 4; ++RH)
        qf[RH] = *(const bf16x8*)(Qb + ((size_t)(b * SS + i0 + RH*16 + lc)) * HH + w*32 + lg*8);
    const f32x4 z4 = {0.f, 0.f, 0.f, 0.f};
    float lsum[4][4] = {};
    const int jend = min(jstart + CHW - 32, (jmax >> 5) << 5);
    bf16x8 kf0 = *(const bf16x8*)(Kb + ((size_t)(b * SS + jstart + lc)) * HH + w*32 + lg*8);
    bf16x8 kf1 = *(const bf16x8*)(Kb + ((size_t)(b * SS + jstart + 16 + lc)) * HH + w*32 + lg*8);
    for (int j0 = jstart; j0 <= jend; j0 += 32) {
        bf16x8 ck0 = kf0, ck1 = kf1;
        if (j0 + 32 <= jend) {
            kf0 = *(const bf16x8*)(Kb + ((size_t)(b * SS + j0 + 32 + lc)) * HH + w*32 + lg*8);
            kf1 = *(const bf16x8*)(Kb + ((size_t)(b * SS + j0 + 48 + lc)) * HH + w*32 + lg*8);
        }
        f32x4 s[4][2];
        #pragma unroll
        for (int RH = 0; RH < 4; ++RH) {
            s[RH][0] = __builtin_amdgcn_mfma_f32_16x16x32_bf16(qf[RH], ck0, z4, 0, 0, 0);
            s[RH][1] = __builtin_amdgcn_mfma_f32_16x16x32_bf16(qf[RH], ck1, z4, 0, 0, 0);
        }
        if (j0 < i0) {          // full tile
            #pragma unroll
            for (int RH = 0; RH < 4; ++RH)
                #pragma unroll
                for (int r = 0; r < 4; ++r)
                    #pragma unroll
                    for (int CH = 0; CH < 2; ++CH)
                        lsum[RH][r] += EXP2F(s[RH][CH][r]);
        } else {                // diagonal region: per-element causal mask
            #pragma unroll
            for (int RH = 0; RH < 4; ++RH)
                #pragma unroll
                for (int r = 0; r < 4; ++r) {
                    const int row = i0 + RH*16 + lg*4 + r;
                    #pragma unroll
                    for (int CH = 0; CH < 2; ++CH) {
                        const int j = j0 + CH*16 + lc;
                        lsum[RH][r] += (j <= row) ? EXP2F(s[RH][CH][r]) : 0.f;
                    }
                }
        }
    }
    #pragma unroll
    for (int RH = 0; RH < 4; ++RH)
        #pragma unroll
        for (int r = 0; r < 4; ++r) {
            float v = lsum[RH][r];
            v += __shfl_xor(v, 1); v += __shfl_xor(v, 2);
            v += __shfl_xor(v, 4); v += __shfl_xor(v, 8);
            if (lc == 0)
                Psum[((size_t)(c * BB + b) * NHH + w) * SS + i0 + RH*16 + lg*4 + r] = v;
        }
}

// ---------------- attention pass 2: 64-ROW Q-tiles, single-buffer Pb.
// Per iteration: 8 indep QK MFMAs, P->LDS, 8 PV MFMAs (own slice, no
// barrier), barrier, 64-row mean (float4), barrier. Active j-tiles [0,T64)
// split among NCO=4 cgs (prefix); extra cgs contribute exact zeros for rows
// whose causal extent is below their tiles, so ffn's ncv prefix-read holds.
__global__ __launch_bounds__(512) void attn_pv(const ushortT* __restrict__ Qb,
        const ushortT* __restrict__ Kb, const ushortT* __restrict__ Vt,
        const int* __restrict__ lengths, const float* __restrict__ Psum,
        ushortT* __restrict__ OPart, float* __restrict__ out_mean) {
    __shared__ __align__(16) ushortT Pb[NHH][64][40];
    __shared__ float invS[NHH][64];
    const int b = blockIdx.z, cg = blockIdx.y;
    const int i0 = (31 - blockIdx.x) << 6;    // 64-row tiles, reversed dispatch
    const int len = lengths[b];
    const int tid = threadIdx.x;
    const int mr = tid >> 3, mc = (tid & 7) << 2;   // mean: 64 rows x 4 cols
    // T = number of active 32-col tiles for this 64-row block
    const int T = (i0 < len) ? ((min(i0 + 63, len - 1) >> 5) + 1) : 0;
    // balanced prefix partition of [0,T): cg<r get q+1 tiles, others q
    const int q = T >> 2, r = T & (NCO - 1);
    const int t0 = cg * q + min(cg, r);
    const int t1 = t0 + q + (cg < r ? 1 : 0);
    if (t0 >= t1) return;
    // inverse denominators for 64 rows x 8 heads (tid covers all 512)
    {
        const int hh = tid >> 6, row = i0 + (tid & 63);
        float rv = 0.f;
        if (row < len && hh < len) {
            float s = 0.f;
            const int ncv = (row >> 8) + 1;           // Psum chunks 0..row/CHW active
            for (int c2 = 0; c2 < ncv; ++c2)
                s += Psum[((size_t)(c2 * BB + b) * NHH + hh) * SS + row];
            rv = (s > 0.f) ? 1.0f / s : 0.f;
        }
        invS[tid >> 6][tid & 63] = rv;
    }
    __syncthreads();
    const int w = tid >> 6, lane = tid & 63;
    const int lg = lane >> 4, lc = lane & 15;
    bf16x8 qf[4];
    #pragma unroll
    for (int RH = 0; RH < 4; ++RH)
        qf[RH] = *(const bf16x8*)(Qb + ((size_t)(b * SS + i0 + RH*16 + lc)) * HH + w*32 + lg*8);
    float invv[4][4];
    #pragma unroll
    for (int RH = 0; RH < 4; ++RH)
        #pragma unroll
        for (int r2 = 0; r2 < 4; ++r2)
            invv[RH][r2] = invS[w][RH*16 + lg*4 + r2];
    // per-head inv (x 1/8) for this thread's mean row
    float invh8[NHH];
    #pragma unroll
    for (int hh = 0; hh < NHH; ++hh)
        invh8[hh] = invS[hh][mr] * 0.125f;
    const f32x4 z4 = {0.f, 0.f, 0.f, 0.f};
    f32x4 O[4][2];
    #pragma unroll
    for (int RH = 0; RH < 4; ++RH) { O[RH][0] = z4; O[RH][1] = z4; }
    const int jstart = t0 << 5;
    bf16x8 kf0 = *(const bf16x8*)(Kb + ((size_t)(b * SS + jstart + lc)) * HH + w*32 + lg*8);
    bf16x8 kf1 = *(const bf16x8*)(Kb + ((size_t)(b * SS + jstart + 16 + lc)) * HH + w*32 + lg*8);
    bf16x8 vf0 = *(const bf16x8*)(Vt + ((size_t)(b * HH + w*32 + lc)) * SS + jstart + lg*8);
    bf16x8 vf1 = *(const bf16x8*)(Vt + ((size_t)(b * HH + w*32 + 16 + lc)) * SS + jstart + lg*8);
    for (int t = t0; t < t1; ++t) {
        const int j0 = t << 5;
        bf16x8 ck0 = kf0, ck1 = kf1, cv0 = vf0, cv1 = vf1;
        if (t + 1 < t1) {
            kf0 = *(const bf16x8*)(Kb + ((size_t)(b * SS + j0 + 32 + lc)) * HH + w*32 + lg*8);
            kf1 = *(const bf16x8*)(Kb + ((size_t)(b * SS + j0 + 48 + lc)) * HH + w*32 + lg*8);
            vf0 = *(const bf16x8*)(Vt + ((size_t)(b * HH + w*32 + lc)) * SS + j0 + 32 + lg*8);
            vf1 = *(const bf16x8*)(Vt + ((size_t)(b * HH + w*32 + 16 + lc)) * SS + j0 + 32 + lg*8);
        }
        f32x4 s[4][2];
        #pragma unroll
        for (int RH = 0; RH < 4; ++RH) {
            s[RH][0] = __builtin_amdgcn_mfma_f32_16x16x32_bf16(qf[RH], ck0, z4, 0, 0, 0);
            s[RH][1] = __builtin_amdgcn_mfma_f32_16x16x32_bf16(qf[RH], ck1, z4, 0, 0, 0);
        }
        if (j0 < i0) {      // full tile: unmasked, unnormalized
            #pragma unroll
            for (int RH = 0; RH < 4; ++RH)
                #pragma unroll
                for (int CH = 0; CH < 2; ++CH)
                    #pragma unroll
                    for (int r2 = 0; r2 < 4; ++r2)
                        Pb[w][RH*16 + lg*4 + r2][CH*16 + lc] =
                            f2bf_rz(EXP2F(s[RH][CH][r2]));
        } else {            // diagonal region: causal mask
            #pragma unroll
            for (int RH = 0; RH < 4; ++RH)
                #pragma unroll
                for (int CH = 0; CH < 2; ++CH)
                    #pragma unroll
                    for (int r2 = 0; r2 < 4; ++r2) {
                        const int row = i0 + RH*16 + lg*4 + r2;
                        const int j = j0 + CH*16 + lc;
                        Pb[w][RH*16 + lg*4 + r2][CH*16 + lc] =
                            (j <= row) ? f2bf_rz(EXP2F(s[RH][CH][r2])) : (ushortT)0;
                    }
        }
        // PV on own wave's Pb slice: wave-internal LDS ordering, no barrier
        #pragma unroll
        for (int RH = 0; RH < 4; ++RH) {
            bf16x8 pa = *(const bf16x8*)&Pb[w][RH*16 + lc][lg*8];
            O[RH][0] = __builtin_amdgcn_mfma_f32_16x16x32_bf16(pa, cv0, O[RH][0], 0, 0, 0);
            O[RH][1] = __builtin_amdgcn_mfma_f32_16x16x32_bf16(pa, cv1, O[RH][1], 0, 0, 0);
        }
        __syncthreads();
        // atten_mean: sum_h e_h * inv_h / 8 (reads all heads -> after barrier)
        float m0 = 0.f, m1 = 0.f, m2 = 0.f, m3 = 0.f;
        #pragma unroll
        for (int ww = 0; ww < NHH; ++ww) {
            ushort4 t4 = *(const ushort4*)&Pb[ww][mr][mc];
            m0 += bf2f(t4.x) * invh8[ww]; m1 += bf2f(t4.y) * invh8[ww];
            m2 += bf2f(t4.z) * invh8[ww]; m3 += bf2f(t4.w) * invh8[ww];
        }
        *(float4*)(out_mean + ((size_t)(b * SS + i0 + mr)) * SS + j0 + mc)
            = make_float4(m0, m1, m2, m3);
        __syncthreads();   // protect Pb overwrite next iteration
    }
    // write partial O for this chunk-group (normalized; rows<len only ever read)
    ushortT* op = OPart + (size_t)cg * ((size_t)BB * SS * HH);
    #pragma unroll
    for (int RH = 0; RH < 4; ++RH)
        #pragma unroll
        for (int DH = 0; DH < 2; ++DH)
            #pragma unroll
            for (int r2 = 0; r2 < 4; ++r2)
                op[((size_t)(b * SS + i0 + RH*16 + lg*4 + r2)) * HH + w*32 + DH*16 + lc] =
                    f2bf(O[RH][DH][r2] * invv[RH][r2]);
}

extern "C" void kernel_launch(void* const* d_in, const int* in_sizes, int n_in,
                              void* d_out, int out_size, void* d_ws, size_t ws_size,
                              hipStream_t stream) {
    const float* x   = (const float*)d_in[0];
    const int* lengths = (const int*)d_in[1];
    const float* Wq  = (const float*)d_in[3];
    const float* bq  = (const float*)d_in[4];
    const float* Wk  = (const float*)d_in[5];
    const float* bk  = (const float*)d_in[6];
    const float* Wv  = (const float*)d_in[7];
    const float* bv  = (const float*)d_in[8];
    const float* W1  = (const float*)d_in[9];
    const float* b1  = (const float*)d_in[10];
    const float* W2  = (const float*)d_in[11];
    const float* b2  = (const float*)d_in[12];
    const float* g1  = (const float*)d_in[13];
    const float* be1 = (const float*)d_in[14];
    const float* g2  = (const float*)d_in[15];
    const float* be2 = (const float*)d_in[16];
    float* out = (float*)d_out;
    float* ws  = (float*)d_ws;

    const size_t NELT = (size_t)BB * SS * HH;     // 2,097,152
    const size_t M1 = 1024 * 1024;

    // ws layout (floats), phase-based reuse:
    // [0,1M)   Psum (512K f32)
    // [1M,2M)  Qbf (bf16)
    // [2M,3M)  Kbf (bf16)
    // [3M,4M)  Vtb (bf16)
    // [4M,6M)  X1N (fp32)
    // [6M,6.16M) Wtb (only z=3 W1t / z=4 W2t slots used)
    // [7M,11M) OPart: NCO chunk-groups x NELT bf16 (1M floats each)
    float*   Psum = ws;
    ushortT* Qbf = (ushortT*)(ws + M1);
    ushortT* Kbf = (ushortT*)(ws + 2 * M1);
    ushortT* Vtb = (ushortT*)(ws + 3 * M1);
    float*   X1N  = ws + 4 * M1;
    ushortT* Wtb = (ushortT*)(ws + 6 * M1);
    ushortT* OPart = (ushortT*)(ws + 7 * M1);

    float* out_y    = out;                        // [B,S,H]
    float* out_len  = out + NELT;                 // [B] as floats
    float* out_mean = out + NELT + 4;             // [B,S,S]

    gemm_qkv<<<dim3(128, 13), 256, 0, stream>>>(x, lengths, out_len,
                                                Wq, bq, Wk, bk, Wv, bv, W1, W2,
                                                Wtb, Qbf, Kbf, Vtb);
    attn_sums<<<dim3(32, NC, 4), 512, 0, stream>>>(Qbf, Kbf, lengths, Psum, out_mean);
    attn_pv<<<dim3(32, NCO, 4), 512, 0, stream>>>(Qbf, Kbf, Vtb, lengths, Psum, OPart, out_mean);
    ffn_fused<<<256, 512, 0, stream>>>(x, OPart, lengths, g1, be1,
                                       Wtb + 3 * 65536, b1, Wtb + 4 * 65536, b2,
                                       g2, be2, X1N, out_y);
}

// Round 16
// 88.777 us; speedup vs baseline: 1.0455x; 1.0455x over previous
//
#include <hip/hip_runtime.h>
#include <math.h>

#define BB 4
#define SS 2048
#define HH 256
#define NHH 8
#define EPSV 1e-5f
#define NC 8
#define CHW (SS/NC)     /* 256 cols per Psum chunk (attn_sums) */
#define NCO 4           /* O chunk-groups in attn_pv (balanced tile split) */
/* 1/sqrt(256) * log2(e): Q pre-scaled so exp(s/16) == exp2(QK^T) */
#define QPRE 0.09016844005556021f

#if __has_builtin(__builtin_amdgcn_exp2f)
#define EXP2F(x) __builtin_amdgcn_exp2f(x)
#else
#define EXP2F(x) __expf((x) * 0.6931471805599453f)
#endif

typedef unsigned short ushortT;
typedef __attribute__((ext_vector_type(8))) short bf16x8;
typedef __attribute__((ext_vector_type(4))) float f32x4;

__device__ inline ushortT f2bf(float f) {          // RNE
    union { float f; unsigned int u; } x; x.f = f;
    unsigned int r = x.u + 0x7FFFu + ((x.u >> 16) & 1u);
    return (ushortT)(r >> 16);
}
__device__ inline ushortT f2bf_rz(float f) {       // truncate (hot path)
    union { float f; unsigned int u; } x; x.f = f;
    return (ushortT)(x.u >> 16);
}
__device__ inline float bf2f(ushortT u) {
    union { unsigned int i; float f; } x; x.i = ((unsigned int)u) << 16;
    return x.f;
}

// ---------------- fused QKV MFMA GEMM; reads x and W fp32 directly (converts
// + transposes W in staging); Q pre-scaled by QPRE; V stored transposed.
// blockIdx.y==12: 128 side blocks transpose W1/W2 -> Wtb (for ffn_fused)
// and write out_len; race-free (no reader of Wtb z=3/4 in this kernel).
__global__ __launch_bounds__(256) void gemm_qkv(const float* __restrict__ X,
        const int* __restrict__ L, float* __restrict__ out_len,
        const float* __restrict__ Wq, const float* __restrict__ bq,
        const float* __restrict__ Wk, const float* __restrict__ bk,
        const float* __restrict__ Wv, const float* __restrict__ bv,
        const float* __restrict__ W1, const float* __restrict__ W2,
        ushortT* __restrict__ Wtb,
        ushortT* __restrict__ Qb, ushortT* __restrict__ Kb,
        ushortT* __restrict__ Vt) {
    __shared__ ushortT As[64][264];
    __shared__ ushortT Ws[64][264];
    const int tid = threadIdx.x;
    if (blockIdx.y == 12) {                    // W1/W2 transpose side blocks
        const int wb = blockIdx.x;             // 0..127
        if (wb == 0 && tid < BB) out_len[tid] = (float)L[tid];
        const int z = 3 + (wb >> 6);
        const int rem = wb & 63;
        const int k0 = (rem >> 3) << 5, n0q = (rem & 7) << 5;
        const float* W = (z == 3) ? W1 : W2;
        float (*tile)[33] = (float(*)[33])&As[0][0];
        const int r = tid >> 3, c4 = (tid & 7) << 2;
        float4 v = *(const float4*)(W + (size_t)(k0 + r) * HH + n0q + c4);
        tile[r][c4+0] = v.x; tile[r][c4+1] = v.y;
        tile[r][c4+2] = v.z; tile[r][c4+3] = v.w;
        __syncthreads();
        ushort4 o;
        o.x = f2bf(tile[c4+0][r]); o.y = f2bf(tile[c4+1][r]);
        o.z = f2bf(tile[c4+2][r]); o.w = f2bf(tile[c4+3][r]);
        *(ushort4*)(Wtb + (size_t)z * 65536 + (size_t)(n0q + r) * HH + k0 + c4) = o;
        return;
    }
    const int wsel = blockIdx.y >> 2;
    const int n0 = (blockIdx.y & 3) << 6;
    const float* W = (wsel == 0) ? Wq : (wsel == 1) ? Wk : Wv;
    const float* bias = (wsel == 0) ? bq : (wsel == 1) ? bk : bv;
    const int m0 = blockIdx.x << 6;
    // stage x strip (fp32 -> bf16)
    #pragma unroll
    for (int t = 0; t < 8; ++t) {
        const int f = t * 256 + tid;
        const int r = f >> 5;
        const int cc = (f & 31) << 3;
        const float* xrow = X + (size_t)(m0 + r) * HH + cc;
        float4 v0 = *(const float4*)xrow;
        float4 v1 = *(const float4*)(xrow + 4);
        bf16x8 o;
        o[0] = (short)f2bf(v0.x); o[1] = (short)f2bf(v0.y);
        o[2] = (short)f2bf(v0.z); o[3] = (short)f2bf(v0.w);
        o[4] = (short)f2bf(v1.x); o[5] = (short)f2bf(v1.y);
        o[6] = (short)f2bf(v1.z); o[7] = (short)f2bf(v1.w);
        *(bf16x8*)&As[r][cc] = o;
    }
    // stage W slice transposed: Ws[n-n0][k] = bf16(W[k][n]); thread owns one
    // n-column, packs 4 consecutive k into a single aligned b64 store.
    {
        const int q = tid >> 6, ln = tid & 63;
        #pragma unroll
        for (int kg = q * 64; kg < q * 64 + 64; kg += 4) {
            ushort4 o;
            o.x = f2bf(W[(size_t)(kg + 0) * HH + n0 + ln]);
            o.y = f2bf(W[(size_t)(kg + 1) * HH + n0 + ln]);
            o.z = f2bf(W[(size_t)(kg + 2) * HH + n0 + ln]);
            o.w = f2bf(W[(size_t)(kg + 3) * HH + n0 + ln]);
            *(ushort4*)&Ws[ln][kg] = o;
        }
    }
    __syncthreads();
    const int w = tid >> 6, lane = tid & 63;
    const int lg = lane >> 4, lc = lane & 15;
    const int wr = (w & 1) << 5, wc = (w >> 1) << 5;
    f32x4 acc[2][2];
    const f32x4 z4 = {0.f, 0.f, 0.f, 0.f};
    acc[0][0] = z4; acc[0][1] = z4; acc[1][0] = z4; acc[1][1] = z4;
    #pragma unroll
    for (int k0 = 0; k0 < 256; k0 += 32) {
        bf16x8 a0 = *(const bf16x8*)&As[wr + lc][k0 + lg*8];
        bf16x8 a1 = *(const bf16x8*)&As[wr + 16 + lc][k0 + lg*8];
        bf16x8 b0 = *(const bf16x8*)&Ws[wc + lc][k0 + lg*8];
        bf16x8 b1 = *(const bf16x8*)&Ws[wc + 16 + lc][k0 + lg*8];
        acc[0][0] = __builtin_amdgcn_mfma_f32_16x16x32_bf16(a0, b0, acc[0][0], 0, 0, 0);
        acc[0][1] = __builtin_amdgcn_mfma_f32_16x16x32_bf16(a0, b1, acc[0][1], 0, 0, 0);
        acc[1][0] = __builtin_amdgcn_mfma_f32_16x16x32_bf16(a1, b0, acc[1][0], 0, 0, 0);
        acc[1][1] = __builtin_amdgcn_mfma_f32_16x16x32_bf16(a1, b1, acc[1][1], 0, 0, 0);
    }
    ushortT* Out = (wsel == 0) ? Qb : Kb;
    #pragma unroll
    for (int RH = 0; RH < 2; ++RH)
        #pragma unroll
        for (int CH = 0; CH < 2; ++CH) {
            const int col = n0 + wc + CH*16 + lc;
            const float bvv = bias[col];
            float v[4];
            #pragma unroll
            for (int r = 0; r < 4; ++r) {
                v[r] = acc[RH][CH][r] + bvv;
                if (wsel == 0) v[r] *= QPRE;
            }
            if (wsel < 2) {
                #pragma unroll
                for (int r = 0; r < 4; ++r) {
                    const int row = m0 + wr + RH*16 + lg*4 + r;
                    Out[(size_t)row * HH + col] = f2bf(v[r]);
                }
            } else {
                const int row0 = m0 + wr + RH*16 + lg*4;
                const int bidx = row0 >> 11, s0 = row0 & (SS - 1);
                ushort4 o;
                o.x = f2bf(v[0]); o.y = f2bf(v[1]); o.z = f2bf(v[2]); o.w = f2bf(v[3]);
                *(ushort4*)(Vt + ((size_t)(bidx * HH + col)) * SS + s0) = o;
            }
        }
}

// ---------------- fully fused FFN: X1N = LN(x + sum OPart); F1 = gelu(X1N@W1
// + b1) held in LDS; out = LN(F1@W2 + b2 + X1N). Block = 32-row strip x 256
// cols, 512 thr (8 waves), 1 block/CU. Row-local: no cross-block deps.
__global__ __launch_bounds__(512) void ffn_fused(const float* __restrict__ x,
        const ushortT* __restrict__ OPart, const int* __restrict__ lengths,
        const float* __restrict__ g1, const float* __restrict__ be1,
        const ushortT* __restrict__ W1t, const float* __restrict__ b1,
        const ushortT* __restrict__ W2t, const float* __restrict__ b2,
        const float* __restrict__ g2, const float* __restrict__ be2,
        float* __restrict__ X1N, float* __restrict__ out) {
    __shared__ ushortT Ws[256][264];       // W1t, then W2t
    __shared__ ushortT As[32][264];        // X1Nb strip, then F1b strip
    __shared__ float redA[8][32];
    __shared__ float redB[8][32];
    const int tid = threadIdx.x;
    const int m0 = blockIdx.x << 5;
    // stage W1t (full 256 x 256)
    #pragma unroll
    for (int t = 0; t < 16; ++t) {
        const int f = t * 512 + tid;
        const int r = f >> 5;
        const int cc = (f & 31) << 3;
        *(bf16x8*)&Ws[r][cc] = *(const bf16x8*)(W1t + (size_t)r * HH + cc);
    }
    const int w = tid >> 6, lane = tid & 63;
    const int lg = lane >> 4, lc = lane & 15;
    // LN phase: wave w owns rows m0 + w*4 .. +3; lane covers cols lane*4..+3
    const int len = lengths[m0 >> 11];
    const int col0 = lane << 2;
    #pragma unroll
    for (int rr = 0; rr < 4; ++rr) {
        const int row = m0 + w * 4 + rr;
        const int i = row & (SS - 1);
        const size_t base = (size_t)row * HH;
        float4 v = *(const float4*)(x + base + col0);
        if (i < len) {
            const int ncv = min(NCO, (i >> 5) + 1);
            for (int cc = 0; cc < ncv; ++cc) {
                ushort4 o = *(const ushort4*)(OPart +
                    (size_t)cc * ((size_t)BB * SS * HH) + base + col0);
                v.x += bf2f(o.x); v.y += bf2f(o.y);
                v.z += bf2f(o.z); v.w += bf2f(o.w);
            }
        }
        float s = v.x + v.y + v.z + v.w;
        #pragma unroll
        for (int o = 1; o < 64; o <<= 1) s += __shfl_xor(s, o);
        const float mu = s * 0.00390625f;
        float4 d = make_float4(v.x - mu, v.y - mu, v.z - mu, v.w - mu);
        float q = d.x*d.x + d.y*d.y + d.z*d.z + d.w*d.w;
        #pragma unroll
        for (int o = 1; o < 64; o <<= 1) q += __shfl_xor(q, o);
        const float rs = rsqrtf(q * 0.00390625f + EPSV);
        float4 res;
        res.x = d.x * rs * g1[col0+0] + be1[col0+0];
        res.y = d.y * rs * g1[col0+1] + be1[col0+1];
        res.z = d.z * rs * g1[col0+2] + be1[col0+2];
        res.w = d.w * rs * g1[col0+3] + be1[col0+3];
        *(float4*)(X1N + base + col0) = res;
        ushort4 rb;
        rb.x = f2bf(res.x); rb.y = f2bf(res.y);
        rb.z = f2bf(res.z); rb.w = f2bf(res.w);
        *(ushort4*)&As[w * 4 + rr][col0] = rb;
    }
    __syncthreads();
    // MFMA phase 1: wave w -> n-tile (w>>1), col-half (w&1); F1 = gelu(.)
    const int n0 = (w >> 1) << 6;
    const int ch = (w & 1) << 5;
    f32x4 acc[2][2];
    const f32x4 z4 = {0.f, 0.f, 0.f, 0.f};
    acc[0][0] = z4; acc[0][1] = z4; acc[1][0] = z4; acc[1][1] = z4;
    #pragma unroll
    for (int k0 = 0; k0 < 256; k0 += 32) {
        bf16x8 a0 = *(const bf16x8*)&As[lc][k0 + lg*8];
        bf16x8 a1 = *(const bf16x8*)&As[16 + lc][k0 + lg*8];
        bf16x8 b0 = *(const bf16x8*)&Ws[n0 + ch + lc][k0 + lg*8];
        bf16x8 b1 = *(const bf16x8*)&Ws[n0 + ch + 16 + lc][k0 + lg*8];
        acc[0][0] = __builtin_amdgcn_mfma_f32_16x16x32_bf16(a0, b0, acc[0][0], 0, 0, 0);
        acc[0][1] = __builtin_amdgcn_mfma_f32_16x16x32_bf16(a0, b1, acc[0][1], 0, 0, 0);
        acc[1][0] = __builtin_amdgcn_mfma_f32_16x16x32_bf16(a1, b0, acc[1][0], 0, 0, 0);
        acc[1][1] = __builtin_amdgcn_mfma_f32_16x16x32_bf16(a1, b1, acc[1][1], 0, 0, 0);
    }
    // gelu in regs
    #pragma unroll
    for (int RH = 0; RH < 2; ++RH)
        #pragma unroll
        for (int CH = 0; CH < 2; ++CH) {
            const float bv = b1[n0 + ch + CH*16 + lc];
            #pragma unroll
            for (int r = 0; r < 4; ++r) {
                float v = acc[RH][CH][r] + bv;
                acc[RH][CH][r] = 0.5f * v * (1.0f + erff(v * 0.70710678118f));
            }
        }
    __syncthreads();   // all MFMA1 reads of As/Ws complete
    // write F1 (bf16) into As; restage W2t into Ws
    #pragma unroll
    for (int RH = 0; RH < 2; ++RH)
        #pragma unroll
        for (int CH = 0; CH < 2; ++CH)
            #pragma unroll
            for (int r = 0; r < 4; ++r)
                As[RH*16 + lg*4 + r][n0 + ch + CH*16 + lc] = f2bf(acc[RH][CH][r]);
    #pragma unroll
    for (int t = 0; t < 16; ++t) {
        const int f = t * 512 + tid;
        const int r = f >> 5;
        const int cc = (f & 31) << 3;
        *(bf16x8*)&Ws[r][cc] = *(const bf16x8*)(W2t + (size_t)r * HH + cc);
    }
    __syncthreads();
    // MFMA phase 2: F2 = F1 @ W2
    acc[0][0] = z4; acc[0][1] = z4; acc[1][0] = z4; acc[1][1] = z4;
    #pragma unroll
    for (int k0 = 0; k0 < 256; k0 += 32) {
        bf16x8 a0 = *(const bf16x8*)&As[lc][k0 + lg*8];
        bf16x8 a1 = *(const bf16x8*)&As[16 + lc][k0 + lg*8];
        bf16x8 b0 = *(const bf16x8*)&Ws[n0 + ch + lc][k0 + lg*8];
        bf16x8 b1 = *(const bf16x8*)&Ws[n0 + ch + 16 + lc][k0 + lg*8];
        acc[0][0] = __builtin_amdgcn_mfma_f32_16x16x32_bf16(a0, b0, acc[0][0], 0, 0, 0);
        acc[0][1] = __builtin_amdgcn_mfma_f32_16x16x32_bf16(a0, b1, acc[0][1], 0, 0, 0);
        acc[1][0] = __builtin_amdgcn_mfma_f32_16x16x32_bf16(a1, b0, acc[1][0], 0, 0, 0);
        acc[1][1] = __builtin_amdgcn_mfma_f32_16x16x32_bf16(a1, b1, acc[1][1], 0, 0, 0);
    }
    // v = acc + b2 + X1N; per-row partial sums over this wave's 32 cols
    float v[2][2][4];
    float rs2[2][4] = {};
    #pragma unroll
    for (int RH = 0; RH < 2; ++RH)
        #pragma unroll
        for (int CH = 0; CH < 2; ++CH) {
            const int col = n0 + ch + CH*16 + lc;
            const float bv = b2[col];
            #pragma unroll
            for (int r = 0; r < 4; ++r) {
                const int row = m0 + RH*16 + lg*4 + r;
                float vv = acc[RH][CH][r] + bv + X1N[(size_t)row * HH + col];
                v[RH][CH][r] = vv;
                rs2[RH][r] += vv;
            }
        }
    #pragma unroll
    for (int RH = 0; RH < 2; ++RH)
        #pragma unroll
        for (int r = 0; r < 4; ++r) {
            rs2[RH][r] += __shfl_xor(rs2[RH][r], 1);
            rs2[RH][r] += __shfl_xor(rs2[RH][r], 2);
            rs2[RH][r] += __shfl_xor(rs2[RH][r], 4);
            rs2[RH][r] += __shfl_xor(rs2[RH][r], 8);
        }
    if (lc == 0) {
        #pragma unroll
        for (int RH = 0; RH < 2; ++RH)
            #pragma unroll
            for (int r = 0; r < 4; ++r)
                redA[w][RH*16 + lg*4 + r] = rs2[RH][r];
    }
    __syncthreads();
    float mu2[2][4];
    #pragma unroll
    for (int RH = 0; RH < 2; ++RH)
        #pragma unroll
        for (int r = 0; r < 4; ++r) {
            const int rl = RH*16 + lg*4 + r;
            mu2[RH][r] = (redA[0][rl] + redA[1][rl] + redA[2][rl] + redA[3][rl]
                        + redA[4][rl] + redA[5][rl] + redA[6][rl] + redA[7][rl])
                       * 0.00390625f;
        }
    float qs[2][4] = {};
    #pragma unroll
    for (int RH = 0; RH < 2; ++RH)
        #pragma unroll
        for (int CH = 0; CH < 2; ++CH)
            #pragma unroll
            for (int r = 0; r < 4; ++r) {
                const float d = v[RH][CH][r] - mu2[RH][r];
                qs[RH][r] += d * d;
            }
    #pragma unroll
    for (int RH = 0; RH < 2; ++RH)
        #pragma unroll
        for (int r = 0; r < 4; ++r) {
            qs[RH][r] += __shfl_xor(qs[RH][r], 1);
            qs[RH][r] += __shfl_xor(qs[RH][r], 2);
            qs[RH][r] += __shfl_xor(qs[RH][r], 4);
            qs[RH][r] += __shfl_xor(qs[RH][r], 8);
        }
    if (lc == 0) {
        #pragma unroll
        for (int RH = 0; RH < 2; ++RH)
            #pragma unroll
            for (int r = 0; r < 4; ++r)
                redB[w][RH*16 + lg*4 + r] = qs[RH][r];
    }
    __syncthreads();
    #pragma unroll
    for (int RH = 0; RH < 2; ++RH)
        #pragma unroll
        for (int r = 0; r < 4; ++r) {
            const int rl = RH*16 + lg*4 + r;
            const float var = (redB[0][rl] + redB[1][rl] + redB[2][rl] + redB[3][rl]
                             + redB[4][rl] + redB[5][rl] + redB[6][rl] + redB[7][rl])
                            * 0.00390625f;
            const float rq = rsqrtf(var + EPSV);
            const int row = m0 + rl;
            #pragma unroll
            for (int CH = 0; CH < 2; ++CH) {
                const int col = n0 + ch + CH*16 + lc;
                out[(size_t)row * HH + col] =
                    (v[RH][CH][r] - mu2[RH][r]) * rq * g2[col] + be2[col];
            }
        }
}

// ---------------- attention pass 1: partial exp2-sums per (chunk, head, row)
// 64-ROW Q-tiles. Also zero-fills the INACTIVE cols of its out_mean chunk.
__global__ __launch_bounds__(512) void attn_sums(const ushortT* __restrict__ Qb,
        const ushortT* __restrict__ Kb, const int* __restrict__ lengths,
        float* __restrict__ Psum, float* __restrict__ out_mean) {
    const int b = blockIdx.z, c = blockIdx.y;
    const int i0 = (31 - blockIdx.x) << 6;    // 64-row tiles, reversed dispatch
    const int len = lengths[b];
    const int tid = threadIdx.x;
    const int w = tid >> 6, lane = tid & 63;
    // zero inactive cols of this chunk; per-row T from its 32-row block
    #pragma unroll
    for (int rr = 0; rr < 8; ++rr) {
        const int row = i0 + w * 8 + rr;
        const int i032 = row & ~31;
        const int Tr = (i032 < len) ? ((min(i032 + 31, len - 1) >> 5) + 1) : 0;
        const int zs = max(Tr * 32 - c * CHW, 0);
        const int col = zs + (lane << 2);
        if (zs < CHW && col < CHW)
            *(float4*)(out_mean + ((size_t)(b * SS + row)) * SS + c * CHW + col)
                = make_float4(0.f, 0.f, 0.f, 0.f);
    }
    const int jmax = min(i0 + 63, len - 1);
    const int jstart = c * CHW;
    if (i0 >= len || jstart > jmax) return;   // never read downstream
    const int lg = lane >> 4, lc = lane & 15;
    bf16x8 qf[4];
    #pragma unroll
    for (int RH = 0; RH < 4; ++RH)
        qf[RH] = *(const bf16x8*)(Qb + ((size_t)(b * SS + i0 + RH*16 + lc)) * HH + w*32 + lg*8);
    const f32x4 z4 = {0.f, 0.f, 0.f, 0.f};
    float lsum[4][4] = {};
    const int jend = min(jstart + CHW - 32, (jmax >> 5) << 5);
    bf16x8 kf0 = *(const bf16x8*)(Kb + ((size_t)(b * SS + jstart + lc)) * HH + w*32 + lg*8);
    bf16x8 kf1 = *(const bf16x8*)(Kb + ((size_t)(b * SS + jstart + 16 + lc)) * HH + w*32 + lg*8);
    for (int j0 = jstart; j0 <= jend; j0 += 32) {
        bf16x8 ck0 = kf0, ck1 = kf1;
        if (j0 + 32 <= jend) {
            kf0 = *(const bf16x8*)(Kb + ((size_t)(b * SS + j0 + 32 + lc)) * HH + w*32 + lg*8);
            kf1 = *(const bf16x8*)(Kb + ((size_t)(b * SS + j0 + 48 + lc)) * HH + w*32 + lg*8);
        }
        f32x4 s[4][2];
        #pragma unroll
        for (int RH = 0; RH < 4; ++RH) {
            s[RH][0] = __builtin_amdgcn_mfma_f32_16x16x32_bf16(qf[RH], ck0, z4, 0, 0, 0);
            s[RH][1] = __builtin_amdgcn_mfma_f32_16x16x32_bf16(qf[RH], ck1, z4, 0, 0, 0);
        }
        if (j0 < i0) {          // full tile
            #pragma unroll
            for (int RH = 0; RH < 4; ++RH)
                #pragma unroll
                for (int r = 0; r < 4; ++r)
                    #pragma unroll
                    for (int CH = 0; CH < 2; ++CH)
                        lsum[RH][r] += EXP2F(s[RH][CH][r]);
        } else {                // diagonal region: per-element causal mask
            #pragma unroll
            for (int RH = 0; RH < 4; ++RH)
                #pragma unroll
                for (int r = 0; r < 4; ++r) {
                    const int row = i0 + RH*16 + lg*4 + r;
                    #pragma unroll
                    for (int CH = 0; CH < 2; ++CH) {
                        const int j = j0 + CH*16 + lc;
                        lsum[RH][r] += (j <= row) ? EXP2F(s[RH][CH][r]) : 0.f;
                    }
                }
        }
    }
    #pragma unroll
    for (int RH = 0; RH < 4; ++RH)
        #pragma unroll
        for (int r = 0; r < 4; ++r) {
            float v = lsum[RH][r];
            v += __shfl_xor(v, 1); v += __shfl_xor(v, 2);
            v += __shfl_xor(v, 4); v += __shfl_xor(v, 8);
            if (lc == 0)
                Psum[((size_t)(c * BB + b) * NHH + w) * SS + i0 + RH*16 + lg*4 + r] = v;
        }
}

// ---------------- attention pass 2: in-block inv + unnormalized P, mean, PV
// 32-row Q-tiles, double-buffer Pb, ONE barrier per iteration (R14 best).
// Active j-tiles [0,T) split equally among NCO=4 cgs (prefix remainder).
// Inactive mean cols pre-zeroed by attn_sums; only active cells written here.
__global__ __launch_bounds__(512) void attn_pv(const ushortT* __restrict__ Qb,
        const ushortT* __restrict__ Kb, const ushortT* __restrict__ Vt,
        const int* __restrict__ lengths, const float* __restrict__ Psum,
        ushortT* __restrict__ OPart, float* __restrict__ out_mean) {
    __shared__ __align__(16) ushortT Pb[2][NHH][32][40];
    __shared__ float invS[NHH][32];
    const int b = blockIdx.z, cg = blockIdx.y;
    const int i0 = (63 - blockIdx.x) << 5;    // reversed: heavy tiles dispatch first
    const int len = lengths[b];
    const int tid = threadIdx.x;
    const int mr = tid >> 4, mc = (tid & 15) << 1;
    float* meanrow = out_mean + ((size_t)(b * SS + i0 + mr)) * SS + mc;
    // T = number of active 32-col tiles for this row-block (0 if rows invalid)
    const int T = (i0 < len) ? ((min(i0 + 31, len - 1) >> 5) + 1) : 0;
    // balanced prefix partition of [0,T): cg<r get q+1 tiles, others q
    const int q = T >> 2, r = T & (NCO - 1);
    const int t0 = cg * q + min(cg, r);
    const int t1 = t0 + q + (cg < r ? 1 : 0);
    if (t0 >= t1) return;
    // inverse denominators for this tile's 32 rows x 8 heads
    if (tid < NHH * 32) {
        const int hh = tid >> 5, row = i0 + (tid & 31);
        float rv = 0.f;
        if (row < len && hh < len) {
            float s = 0.f;
            const int ncv = (row >> 8) + 1;           // Psum chunks 0..row/CHW active
            for (int c2 = 0; c2 < ncv; ++c2)
                s += Psum[((size_t)(c2 * BB + b) * NHH + hh) * SS + row];
            rv = (s > 0.f) ? 1.0f / s : 0.f;
        }
        invS[hh][tid & 31] = rv;
    }
    __syncthreads();
    const int w = tid >> 6, lane = tid & 63;
    const int lg = lane >> 4, lc = lane & 15;
    bf16x8 qf[2];
    #pragma unroll
    for (int RH = 0; RH < 2; ++RH)
        qf[RH] = *(const bf16x8*)(Qb + ((size_t)(b * SS + i0 + RH*16 + lc)) * HH + w*32 + lg*8);
    float invv[2][4];
    #pragma unroll
    for (int RH = 0; RH < 2; ++RH)
        #pragma unroll
        for (int r2 = 0; r2 < 4; ++r2)
            invv[RH][r2] = invS[w][RH*16 + lg*4 + r2];
    // per-head inv (x 1/8) for this thread's mean row
    float invh8[NHH];
    #pragma unroll
    for (int hh = 0; hh < NHH; ++hh)
        invh8[hh] = invS[hh][mr] * 0.125f;
    const f32x4 z4 = {0.f, 0.f, 0.f, 0.f};
    f32x4 O[2][2];
    O[0][0] = z4; O[0][1] = z4; O[1][0] = z4; O[1][1] = z4;
    const int jstart = t0 << 5;
    bf16x8 kf0 = *(const bf16x8*)(Kb + ((size_t)(b * SS + jstart + lc)) * HH + w*32 + lg*8);
    bf16x8 kf1 = *(const bf16x8*)(Kb + ((size_t)(b * SS + jstart + 16 + lc)) * HH + w*32 + lg*8);
    bf16x8 vf0 = *(const bf16x8*)(Vt + ((size_t)(b * HH + w*32 + lc)) * SS + jstart + lg*8);
    bf16x8 vf1 = *(const bf16x8*)(Vt + ((size_t)(b * HH + w*32 + 16 + lc)) * SS + jstart + lg*8);
    for (int t = t0; t < t1; ++t) {
        const int j0 = t << 5;
        const int par = t & 1;
        bf16x8 ck0 = kf0, ck1 = kf1, cv0 = vf0, cv1 = vf1;
        if (t + 1 < t1) {
            kf0 = *(const bf16x8*)(Kb + ((size_t)(b * SS + j0 + 32 + lc)) * HH + w*32 + lg*8);
            kf1 = *(const bf16x8*)(Kb + ((size_t)(b * SS + j0 + 48 + lc)) * HH + w*32 + lg*8);
            vf0 = *(const bf16x8*)(Vt + ((size_t)(b * HH + w*32 + lc)) * SS + j0 + 32 + lg*8);
            vf1 = *(const bf16x8*)(Vt + ((size_t)(b * HH + w*32 + 16 + lc)) * SS + j0 + 32 + lg*8);
        }
        f32x4 s[2][2];
        #pragma unroll
        for (int RH = 0; RH < 2; ++RH) {
            s[RH][0] = __builtin_amdgcn_mfma_f32_16x16x32_bf16(qf[RH], ck0, z4, 0, 0, 0);
            s[RH][1] = __builtin_amdgcn_mfma_f32_16x16x32_bf16(qf[RH], ck1, z4, 0, 0, 0);
        }
        if (j0 < i0) {      // full tile: unmasked, unnormalized
            #pragma unroll
            for (int RH = 0; RH < 2; ++RH)
                #pragma unroll
                for (int CH = 0; CH < 2; ++CH)
                    #pragma unroll
                    for (int r2 = 0; r2 < 4; ++r2)
                        Pb[par][w][RH*16 + lg*4 + r2][CH*16 + lc] =
                            f2bf_rz(EXP2F(s[RH][CH][r2]));
        } else {            // diagonal: causal mask
            #pragma unroll
            for (int RH = 0; RH < 2; ++RH)
                #pragma unroll
                for (int CH = 0; CH < 2; ++CH)
                    #pragma unroll
                    for (int r2 = 0; r2 < 4; ++r2) {
                        const int row = i0 + RH*16 + lg*4 + r2;
                        const int j = j0 + CH*16 + lc;
                        Pb[par][w][RH*16 + lg*4 + r2][CH*16 + lc] =
                            (j <= row) ? f2bf_rz(EXP2F(s[RH][CH][r2])) : (ushortT)0;
                    }
        }
        // PV on own wave's Pb slice: wave-internal LDS ordering, no barrier
        #pragma unroll
        for (int RH = 0; RH < 2; ++RH) {
            bf16x8 pa = *(const bf16x8*)&Pb[par][w][RH*16 + lc][lg*8];
            O[RH][0] = __builtin_amdgcn_mfma_f32_16x16x32_bf16(pa, cv0, O[RH][0], 0, 0, 0);
            O[RH][1] = __builtin_amdgcn_mfma_f32_16x16x32_bf16(pa, cv1, O[RH][1], 0, 0, 0);
        }
        __syncthreads();
        // atten_mean: sum_h e_h * inv_h / 8 (reads all heads -> after barrier)
        float m0 = 0.f, m1 = 0.f;
        #pragma unroll
        for (int ww = 0; ww < NHH; ++ww) {
            ushort2 t2 = *(const ushort2*)&Pb[par][ww][mr][mc];
            m0 += bf2f(t2.x) * invh8[ww]; m1 += bf2f(t2.y) * invh8[ww];
        }
        *(float2*)(meanrow + j0) = make_float2(m0, m1);
    }
    // write partial O for this chunk-group (normalized; rows<len only ever read)
    ushortT* op = OPart + (size_t)cg * ((size_t)BB * SS * HH);
    #pragma unroll
    for (int RH = 0; RH < 2; ++RH)
        #pragma unroll
        for (int DH = 0; DH < 2; ++DH)
            #pragma unroll
            for (int r2 = 0; r2 < 4; ++r2)
                op[((size_t)(b * SS + i0 + RH*16 + lg*4 + r2)) * HH + w*32 + DH*16 + lc] =
                    f2bf(O[RH][DH][r2] * invv[RH][r2]);
}

extern "C" void kernel_launch(void* const* d_in, const int* in_sizes, int n_in,
                              void* d_out, int out_size, void* d_ws, size_t ws_size,
                              hipStream_t stream) {
    const float* x   = (const float*)d_in[0];
    const int* lengths = (const int*)d_in[1];
    const float* Wq  = (const float*)d_in[3];
    const float* bq  = (const float*)d_in[4];
    const float* Wk  = (const float*)d_in[5];
    const float* bk  = (const float*)d_in[6];
    const float* Wv  = (const float*)d_in[7];
    const float* bv  = (const float*)d_in[8];
    const float* W1  = (const float*)d_in[9];
    const float* b1  = (const float*)d_in[10];
    const float* W2  = (const float*)d_in[11];
    const float* b2  = (const float*)d_in[12];
    const float* g1  = (const float*)d_in[13];
    const float* be1 = (const float*)d_in[14];
    const float* g2  = (const float*)d_in[15];
    const float* be2 = (const float*)d_in[16];
    float* out = (float*)d_out;
    float* ws  = (float*)d_ws;

    const size_t NELT = (size_t)BB * SS * HH;     // 2,097,152
    const size_t M1 = 1024 * 1024;

    // ws layout (floats), phase-based reuse:
    // [0,1M)   Psum (512K f32)
    // [1M,2M)  Qbf (bf16)
    // [2M,3M)  Kbf (bf16)
    // [3M,4M)  Vtb (bf16)
    // [4M,6M)  X1N (fp32)
    // [6M,6.16M) Wtb (only z=3 W1t / z=4 W2t slots used)
    // [7M,11M) OPart: NCO chunk-groups x NELT bf16 (1M floats each)
    float*   Psum = ws;
    ushortT* Qbf = (ushortT*)(ws + M1);
    ushortT* Kbf = (ushortT*)(ws + 2 * M1);
    ushortT* Vtb = (ushortT*)(ws + 3 * M1);
    float*   X1N  = ws + 4 * M1;
    ushortT* Wtb = (ushortT*)(ws + 6 * M1);
    ushortT* OPart = (ushortT*)(ws + 7 * M1);

    float* out_y    = out;                        // [B,S,H]
    float* out_len  = out + NELT;                 // [B] as floats
    float* out_mean = out + NELT + 4;             // [B,S,S]

    gemm_qkv<<<dim3(128, 13), 256, 0, stream>>>(x, lengths, out_len,
                                                Wq, bq, Wk, bk, Wv, bv, W1, W2,
                                                Wtb, Qbf, Kbf, Vtb);
    attn_sums<<<dim3(32, NC, 4), 512, 0, stream>>>(Qbf, Kbf, lengths, Psum, out_mean);
    attn_pv<<<dim3(64, NCO, 4), 512, 0, stream>>>(Qbf, Kbf, Vtb, lengths, Psum, OPart, out_mean);
    ffn_fused<<<256, 512, 0, stream>>>(x, OPart, lengths, g1, be1,
                                       Wtb + 3 * 65536, b1, Wtb + 4 * 65536, b2,
                                       g2, be2, X1N, out_y);
}